// Round 5
// baseline (187.829 us; speedup 1.0000x reference)
//
#include <hip/hip_runtime.h>
#include <hip/hip_bf16.h>

#pragma clang fp contract(off)

#define B_N 32
#define A_N 32526
#define C_N 20
#define K_N 1000
#define CAND_MAX 32768   // worst case: all scores equal -> all candidates

typedef unsigned long long u64;

// ---------------------------------------------------------------- kernel 1
// pscore[b,a] = sigmoid(max_c logits)  (sigmoid monotone => max commutes)
// grid-stride, high occupancy: this kernel carries the 83 MB pcls read.
__global__ void k1_score(const float* __restrict__ pcls,
                         float* __restrict__ pscore, int total)
{
    int stride = gridDim.x * blockDim.x;
    for (int t = blockIdx.x * blockDim.x + threadIdx.x; t < total; t += stride) {
        const float4* p = (const float4*)(pcls + (size_t)t * C_N);
        float m = -INFINITY;
#pragma unroll
        for (int q = 0; q < 5; ++q) {
            float4 v = p[q];
            m = fmaxf(m, fmaxf(fmaxf(v.x, v.y), fmaxf(v.z, v.w)));
        }
        double e = exp(-(double)m);     // correctly-rounded f32 sigmoid path
        pscore[t] = (float)(1.0 / (1.0 + e));
    }
}

// ---------------------------------------------------------------- kernel 2
// per batch: V = exact 1000th-largest score VALUE (30-bit descent, 15 packed
// 2-bit rounds, 1 barrier each); compact all keys with score >= V (>=1000,
// typically exactly 1000; value-ties resolved later by full-key rank).
__global__ void __launch_bounds__(1024)
k2_select(const float* __restrict__ pscore,
          u64* __restrict__ winuns, unsigned* __restrict__ ncand)
{
    const int b = blockIdx.x;
    const int tid = threadIdx.x, lane = tid & 63, wv = tid >> 6;
    __shared__ u64 wsum[2][16];
    __shared__ unsigned cnt_s;
    if (tid == 0) cnt_s = 0;

    const float* ps = pscore + (size_t)b * A_N;
    unsigned key[32];                        // coalesced: a = tid + i*1024
#pragma unroll
    for (int i = 0; i < 32; ++i) {
        int a = tid + i * 1024;
        key[i] = (a < A_N) ? __float_as_uint(ps[a]) : 0u;
    }

    int slot = 0;
    auto bs3 = [&](unsigned a, unsigned b2, unsigned c) -> u64 {
        u64 s = (u64)a | ((u64)b2 << 21) | ((u64)c << 42);
#pragma unroll
        for (int off = 32; off > 0; off >>= 1) s += __shfl_down(s, off);
        if (lane == 0) wsum[slot][wv] = s;
        __syncthreads();
        u64 t = 0;
#pragma unroll
        for (int w = 0; w < 16; ++w) t += wsum[slot][w];
        slot ^= 1;
        return t;
    };

    // value descent over bits 29..0 (score bits <= 0x3F800000 < 2^30)
    unsigned V = 0;
#pragma unroll 1
    for (int sh = 28; sh >= 0; sh -= 2) {
        unsigned X1 = V | (1u << sh), X2 = V | (2u << sh), X3 = V | (3u << sh);
        unsigned c1 = 0, c2 = 0, c3 = 0;
#pragma unroll
        for (int i = 0; i < 32; ++i) {
            unsigned k = key[i];
            c1 += (k >= X1); c2 += (k >= X2); c3 += (k >= X3);
        }
        u64 s = bs3(c1, c2, c3);
        unsigned s1 = (unsigned)(s & 0x1FFFFFu);
        unsigned s2 = (unsigned)((s >> 21) & 0x1FFFFFu);
        unsigned s3 = (unsigned)(s >> 42);
        if (s3 >= K_N) V = X3; else if (s2 >= K_N) V = X2; else if (s1 >= K_N) V = X1;
    }

    // compact candidates (score >= V); count(score>V) < 1000 <= count(score>=V)
    u64* wb = winuns + (size_t)b * CAND_MAX;
#pragma unroll
    for (int i = 0; i < 32; ++i) {
        int a = tid + i * 1024;
        bool win = (a < A_N) && (key[i] >= V);
        u64 wm = __ballot(win);
        unsigned base = 0;
        if (lane == 0 && wm) base = atomicAdd(&cnt_s, (unsigned)__popcll(wm));
        base = __shfl(base, 0);
        if (win)
            wb[base + (unsigned)__popcll(wm & ((1ull << lane) - 1ull))] =
                ((u64)key[i] << 32) | (u64)(0xFFFFFFFFu - (unsigned)a);
    }
    __syncthreads();
    if (tid == 0) ncand[b] = cnt_s;
}

// ---------------------------------------------------------------- kernel 2c
// rank each candidate by its full unique key (desc score, asc index) and
// scatter ranks < 1000. rank among candidates == global rank.
__global__ void __launch_bounds__(1024)
k2c_rank(const u64* __restrict__ winuns, const unsigned* __restrict__ ncand,
         int* __restrict__ topi, float* __restrict__ topv)
{
    const int bc = blockIdx.x;   // 0..7
    const int b = blockIdx.y;
    const int tid = threadIdx.x;
    __shared__ u64 chunk[1024];
    const unsigned n = ncand[b];
    const u64* wb = winuns + (size_t)b * CAND_MAX;

    for (unsigned c0 = bc * 1024; c0 < n; c0 += 8192) {
        unsigned c = c0 + tid;
        u64 myk = (c < n) ? wb[c] : 0ull;
        unsigned rank = 0;
        for (unsigned j0 = 0; j0 < n; j0 += 1024) {
            __syncthreads();
            if (j0 + tid < n) chunk[tid] = wb[j0 + tid];
            __syncthreads();
            unsigned lim = (n - j0 < 1024u) ? (n - j0) : 1024u;
            for (unsigned j = 0; j < lim; ++j) rank += (chunk[j] > myk);
        }
        if (c < n && rank < K_N) {
            topi[(size_t)b * K_N + rank] = (int)(0xFFFFFFFFu - (unsigned)(myk & 0xFFFFFFFFull));
            topv[(size_t)b * K_N + rank] = __uint_as_float((unsigned)(myk >> 32));
        }
    }
}

// ---------------------------------------------------------------- kernel 3
__global__ void k3_decode(const float* __restrict__ ptxywh,
                          const float* __restrict__ pcls,
                          const float* __restrict__ anchors,
                          const int* __restrict__ topi,
                          float4* __restrict__ boxesws,
                          int* __restrict__ labelsws,
                          float* __restrict__ out)
{
    int t = blockIdx.x * blockDim.x + threadIdx.x;
    if (t >= B_N * K_N) return;
    int b = t / K_N;
    int a = topi[t];

    float4 tb = ((const float4*)ptxywh)[(size_t)b * A_N + a];
    float4 an = ((const float4*)anchors)[a];

    float xx = an.x + (tb.x * 0.1f) * an.z;
    float yy = an.y + (tb.y * 0.1f) * an.w;
    float ww = an.z * (float)exp((double)(tb.z * 0.2f));
    float hh = an.w * (float)exp((double)(tb.w * 0.2f));
    float hw = ww * 0.5f, hh2 = hh * 0.5f;
    boxesws[t] = make_float4(xx - hw, yy - hh2, xx + hw, yy + hh2);

    const float4* pc = (const float4*)(pcls + ((size_t)b * A_N + a) * C_N);
    float m = -INFINITY; int lab = 0;
#pragma unroll
    for (int q = 0; q < 5; ++q) {
        float4 v = pc[q];
        if (v.x > m) { m = v.x; lab = q * 4 + 0; }
        if (v.y > m) { m = v.y; lab = q * 4 + 1; }
        if (v.z > m) { m = v.z; lab = q * 4 + 2; }
        if (v.w > m) { m = v.w; lab = q * 4 + 3; }
    }
    labelsws[t] = lab + 1;

    out[t] = (float)b;                                 // ids_batch
    out[5 * B_N * K_N + t] = (float)(lab + 1);         // labels
}

// ---------------------------------------------------------------- kernel 4
// suppression bitmask, TRANSPOSED layout: maskT[(b*16 + w)*1024 + i]
__global__ void k4_mask(const float4* __restrict__ boxesws,
                        const int* __restrict__ labelsws,
                        u64* __restrict__ maskT)
{
    const int b = blockIdx.y;
    const int tid = threadIdx.x;
    __shared__ float4 obox[K_N];
    __shared__ float oarea[K_N];

    for (int idx = tid; idx < K_N; idx += 256) {
        float4 bx = boxesws[(size_t)b * K_N + idx];
        float off = (float)labelsws[(size_t)b * K_N + idx] * 10.0f;
        float l = bx.x + off, t2 = bx.y + off, r = bx.z + off, bo = bx.w + off;
        obox[idx] = make_float4(l, t2, r, bo);
        oarea[idx] = (r - l) * (bo - t2);
    }
    __syncthreads();

    const int il = tid & 63;
    const int i = blockIdx.x * 64 + il;
    if (i >= K_N) return;
    float4 bi = obox[i];
    float ai = oarea[i];
#pragma unroll
    for (int p = 0; p < 4; ++p) {
        int w = (tid >> 6) + p * 4;
        u64 word = 0ull;
        for (int jj = 0; jj < 64; ++jj) {
            int j = w * 64 + jj;
            if (j < K_N && j != i) {
                float4 bj = obox[j];
                float lx = fmaxf(bi.x, bj.x);
                float ly = fmaxf(bi.y, bj.y);
                float rx = fminf(bi.z, bj.z);
                float ry = fminf(bi.w, bj.w);
                float wx = fmaxf(rx - lx, 0.0f);
                float wy = fmaxf(ry - ly, 0.0f);
                float inter = wx * wy;
                float uni = ai + oarea[j] - inter;
                float den = fmaxf(uni, 1e-9f);
                float iou = inter / den;
                if (iou > 0.5f) word |= (1ull << jj);
            }
        }
        maskT[((size_t)b * 16 + w) * 1024 + i] = word;
    }
}

// ---------------------------------------------------------------- kernel 5
// greedy NMS scan. Diagonal 64x64 block in scalar registers via readlane;
// pure-SALU pend chain; final pend == keep set.
__global__ void __launch_bounds__(1024)
k5_scan(const u64* __restrict__ maskT,
        const float* __restrict__ topv,
        const float4* __restrict__ boxesws,
        float* __restrict__ out)
{
    const int b = blockIdx.x;
    const int t = threadIdx.x;
    const int lane = t & 63;
    const int wv = t >> 6;              // wave id == chunk id

    __shared__ u64 keeparr[16];

    const u64* mt = maskT + (size_t)b * 16 * 1024;
    const float* tv = topv + (size_t)b * K_N;

    const bool inr = t < K_N;
    const float myv = tv[inr ? t : 0];
    const bool valid = inr && (myv >= 0.5f);
    bool suppressed = false;

    u64 wcur = inr ? mt[t] : 0ull;      // my row's word 0 (coalesced)

#pragma unroll 1
    for (int d = 0; d < 16; ++d) {
        u64 wnext = 0ull;
        if (d < 15 && inr) wnext = mt[(size_t)(d + 1) * 1024 + t];  // prefetch
        if (wv == d) {
            unsigned wlo = (unsigned)wcur, whi = (unsigned)(wcur >> 32);
            u64 pend = __ballot(valid && !suppressed);
#pragma unroll
            for (int r = 0; r < 64; ++r) {
                u64 roww = ((u64)(unsigned)__builtin_amdgcn_readlane(whi, r) << 32)
                         |  (u64)(unsigned)__builtin_amdgcn_readlane(wlo, r);
                u64 take = ((pend >> r) & 1ull) ? roww : 0ull;
                pend &= ~take;
            }
            if (lane == 0) keeparr[d] = pend;   // pend == keep set for chunk d
        }
        __syncthreads();
        if (wcur & keeparr[d]) suppressed = true;
        wcur = wnext;
    }

    // outputs: boxes*keep, scores*keep, keep
    float* out_boxes  = out + (size_t)B_N * K_N;          // 32000
    float* out_scores = out + (size_t)6 * B_N * K_N;      // 192000
    float* out_keep   = out + (size_t)7 * B_N * K_N;      // 224000
    if (inr) {
        float kf = ((keeparr[wv] >> lane) & 1ull) ? 1.0f : 0.0f;
        float4 bx = boxesws[(size_t)b * K_N + t];
        size_t o = (size_t)b * K_N + t;
        out_boxes[o * 4 + 0] = bx.x * kf;
        out_boxes[o * 4 + 1] = bx.y * kf;
        out_boxes[o * 4 + 2] = bx.z * kf;
        out_boxes[o * 4 + 3] = bx.w * kf;
        out_scores[o] = myv * kf;
        out_keep[o] = kf;
    }
}

// ---------------------------------------------------------------- launch
extern "C" void kernel_launch(void* const* d_in, const int* in_sizes, int n_in,
                              void* d_out, int out_size, void* d_ws, size_t ws_size,
                              hipStream_t stream)
{
    const float* ptxywh  = (const float*)d_in[0];
    const float* pcls    = (const float*)d_in[1];
    const float* anchors = (const float*)d_in[2];
    float* out = (float*)d_out;

    char* ws = (char*)d_ws;
    size_t o = 0;
    float* pscore = (float*)(ws + o);        o += (size_t)B_N * A_N * 4;        // 4.16 MB
    u64* winuns   = (u64*)(ws + o);          o += (size_t)B_N * CAND_MAX * 8;   // 8.39 MB
    unsigned* ncand = (unsigned*)(ws + o);   o += 256;
    int*   topi = (int*)(ws + o);            o += (size_t)B_N * K_N * 4;
    float* topv = (float*)(ws + o);          o += (size_t)B_N * K_N * 4;
    float4* boxesws = (float4*)(ws + o);     o += (size_t)B_N * K_N * 16;
    int* labelsws   = (int*)(ws + o);        o += (size_t)B_N * K_N * 4;
    u64* maskT = (u64*)(ws + o);             o += (size_t)B_N * 16 * 1024 * 8;  // 4.19 MB
    // total ~18 MB

    int total = B_N * A_N;
    k1_score<<<2048, 256, 0, stream>>>(pcls, pscore, total);
    k2_select<<<B_N, 1024, 0, stream>>>(pscore, winuns, ncand);
    k2c_rank<<<dim3(8, B_N), 1024, 0, stream>>>(winuns, ncand, topi, topv);
    k3_decode<<<(B_N * K_N + 255) / 256, 256, 0, stream>>>(ptxywh, pcls, anchors,
                                                           topi, boxesws, labelsws, out);
    k4_mask<<<dim3(16, B_N), 256, 0, stream>>>(boxesws, labelsws, maskT);
    k5_scan<<<B_N, 1024, 0, stream>>>(maskT, topv, boxesws, out);
}

// Round 6
// 136.709 us; speedup vs baseline: 1.3739x; 1.3739x over previous
//
#include <hip/hip_runtime.h>
#include <hip/hip_bf16.h>

#pragma clang fp contract(off)

#define B_N 32
#define A_N 32526
#define C_N 20
#define K_N 1000
#define CAND_MAX 32768   // worst case: all scores equal -> all candidates

typedef unsigned long long u64;

// ---------------------------------------------------------------- kernel 1
// pscore[b,a] = sigmoid(max_c logits)  (sigmoid monotone => max commutes)
__global__ void k1_score(const float* __restrict__ pcls,
                         float* __restrict__ pscore, int total)
{
    int stride = gridDim.x * blockDim.x;
    for (int t = blockIdx.x * blockDim.x + threadIdx.x; t < total; t += stride) {
        const float4* p = (const float4*)(pcls + (size_t)t * C_N);
        float m = -INFINITY;
#pragma unroll
        for (int q = 0; q < 5; ++q) {
            float4 v = p[q];
            m = fmaxf(m, fmaxf(fmaxf(v.x, v.y), fmaxf(v.z, v.w)));
        }
        double e = exp(-(double)m);     // correctly-rounded f32 sigmoid path
        pscore[t] = (float)(1.0 / (1.0 + e));
    }
}

// ---------------------------------------------------------------- kernel 2
// per batch: V = exact 1000th-largest score VALUE (15 packed 2-bit rounds,
// 1 barrier each); compact all keys with score >= V (>=1000, typically
// exactly 1000; value-ties resolved later by full-key rank).
__global__ void __launch_bounds__(1024)
k2_select(const float* __restrict__ pscore,
          u64* __restrict__ winuns, unsigned* __restrict__ ncand)
{
    const int b = blockIdx.x;
    const int tid = threadIdx.x, lane = tid & 63, wv = tid >> 6;
    __shared__ u64 wsum[2][16];
    __shared__ unsigned cnt_s;
    if (tid == 0) cnt_s = 0;

    const float* ps = pscore + (size_t)b * A_N;
    unsigned key[32];                        // coalesced: a = tid + i*1024
#pragma unroll
    for (int i = 0; i < 32; ++i) {
        int a = tid + i * 1024;
        key[i] = (a < A_N) ? __float_as_uint(ps[a]) : 0u;
    }

    int slot = 0;
    auto bs3 = [&](unsigned a, unsigned b2, unsigned c) -> u64 {
        u64 s = (u64)a | ((u64)b2 << 21) | ((u64)c << 42);
#pragma unroll
        for (int off = 32; off > 0; off >>= 1) s += __shfl_down(s, off);
        if (lane == 0) wsum[slot][wv] = s;
        __syncthreads();
        u64 t = 0;
#pragma unroll
        for (int w = 0; w < 16; ++w) t += wsum[slot][w];
        slot ^= 1;
        return t;
    };

    // value descent over bits 29..0 (score bits <= 0x3F800000 < 2^30)
    unsigned V = 0;
#pragma unroll 1
    for (int sh = 28; sh >= 0; sh -= 2) {
        unsigned X1 = V | (1u << sh), X2 = V | (2u << sh), X3 = V | (3u << sh);
        unsigned c1 = 0, c2 = 0, c3 = 0;
#pragma unroll
        for (int i = 0; i < 32; ++i) {
            unsigned k = key[i];
            c1 += (k >= X1); c2 += (k >= X2); c3 += (k >= X3);
        }
        u64 s = bs3(c1, c2, c3);
        unsigned s1 = (unsigned)(s & 0x1FFFFFu);
        unsigned s2 = (unsigned)((s >> 21) & 0x1FFFFFu);
        unsigned s3 = (unsigned)(s >> 42);
        if (s3 >= K_N) V = X3; else if (s2 >= K_N) V = X2; else if (s1 >= K_N) V = X1;
    }

    // compact candidates (score >= V); count(score>V) < 1000 <= count(score>=V)
    u64* wb = winuns + (size_t)b * CAND_MAX;
#pragma unroll
    for (int i = 0; i < 32; ++i) {
        int a = tid + i * 1024;
        bool win = (a < A_N) && (key[i] >= V);
        u64 wm = __ballot(win);
        unsigned base = 0;
        if (lane == 0 && wm) base = atomicAdd(&cnt_s, (unsigned)__popcll(wm));
        base = __shfl(base, 0);
        if (win)
            wb[base + (unsigned)__popcll(wm & ((1ull << lane) - 1ull))] =
                ((u64)key[i] << 32) | (u64)(0xFFFFFFFFu - (unsigned)a);
    }
    __syncthreads();
    if (tid == 0) ncand[b] = cnt_s;
}

// ---------------------------------------------------------------- kernel 2c
// rank each candidate by its full unique key (desc score, asc index);
// rank among candidates == global rank. Ranks < 1000 ALSO do the decode
// (fused former k3): box decode, argmax label, ids/labels outputs.
// 8 threads per winner; seg scans keys j == seg (mod 8)  -> the 8 segment
// addresses per wave hit 8 distinct LDS banks (conflict-free broadcast).
__global__ void __launch_bounds__(1024)
k2c_rank_decode(const u64* __restrict__ winuns, const unsigned* __restrict__ ncand,
                const float* __restrict__ ptxywh,
                const float* __restrict__ pcls,
                const float* __restrict__ anchors,
                float* __restrict__ topv,
                float4* __restrict__ boxesws,
                int* __restrict__ labelsws,
                float* __restrict__ out)
{
    const int bc = blockIdx.x;   // 0..7
    const int b = blockIdx.y;
    const int tid = threadIdx.x;
    __shared__ u64 chunk[1024];
    const unsigned n = ncand[b];
    const u64* wb = winuns + (size_t)b * CAND_MAX;

    const int wl = tid >> 3;     // winner slot within pass: 0..127
    const int seg = tid & 7;

    for (unsigned w0 = bc * 128u; w0 < n; w0 += 1024u) {
        unsigned w = w0 + (unsigned)wl;
        bool act = (w < n);
        u64 myk = act ? wb[w] : 0ull;
        unsigned cnt = 0;
        for (unsigned j0 = 0; j0 < n; j0 += 1024u) {
            __syncthreads();
            unsigned j = j0 + tid;
            chunk[tid] = (j < n) ? wb[j] : 0ull;   // pad 0: never > myk
            __syncthreads();
#pragma unroll 16
            for (int jj = 0; jj < 128; ++jj)
                cnt += (chunk[jj * 8 + seg] > myk);
        }
        cnt += __shfl_xor(cnt, 1);
        cnt += __shfl_xor(cnt, 2);
        cnt += __shfl_xor(cnt, 4);
        if (act && seg == 0 && cnt < K_N) {
            unsigned rank = cnt;
            int a = (int)(0xFFFFFFFFu - (unsigned)(myk & 0xFFFFFFFFull));
            size_t t = (size_t)b * K_N + rank;
            topv[t] = __uint_as_float((unsigned)(myk >> 32));

            // ---- fused decode (exact former-k3 math) ----
            float4 tb = ((const float4*)ptxywh)[(size_t)b * A_N + a];
            float4 an = ((const float4*)anchors)[a];
            float xx = an.x + (tb.x * 0.1f) * an.z;
            float yy = an.y + (tb.y * 0.1f) * an.w;
            float ww = an.z * (float)exp((double)(tb.z * 0.2f));
            float hh = an.w * (float)exp((double)(tb.w * 0.2f));
            float hw = ww * 0.5f, hh2 = hh * 0.5f;
            boxesws[t] = make_float4(xx - hw, yy - hh2, xx + hw, yy + hh2);

            const float4* pc = (const float4*)(pcls + ((size_t)b * A_N + a) * C_N);
            float m = -INFINITY; int lab = 0;
#pragma unroll
            for (int q = 0; q < 5; ++q) {
                float4 v = pc[q];
                if (v.x > m) { m = v.x; lab = q * 4 + 0; }
                if (v.y > m) { m = v.y; lab = q * 4 + 1; }
                if (v.z > m) { m = v.z; lab = q * 4 + 2; }
                if (v.w > m) { m = v.w; lab = q * 4 + 3; }
            }
            labelsws[t] = lab + 1;

            out[t] = (float)b;                          // ids_batch
            out[5 * B_N * K_N + t] = (float)(lab + 1);  // labels
        }
    }
}

// ---------------------------------------------------------------- kernel 4
// suppression bitmask, TRANSPOSED layout: maskT[(b*16 + w)*1024 + i]
__global__ void k4_mask(const float4* __restrict__ boxesws,
                        const int* __restrict__ labelsws,
                        u64* __restrict__ maskT)
{
    const int b = blockIdx.y;
    const int tid = threadIdx.x;
    __shared__ float4 obox[K_N];
    __shared__ float oarea[K_N];

    for (int idx = tid; idx < K_N; idx += 256) {
        float4 bx = boxesws[(size_t)b * K_N + idx];
        float off = (float)labelsws[(size_t)b * K_N + idx] * 10.0f;
        float l = bx.x + off, t2 = bx.y + off, r = bx.z + off, bo = bx.w + off;
        obox[idx] = make_float4(l, t2, r, bo);
        oarea[idx] = (r - l) * (bo - t2);
    }
    __syncthreads();

    const int il = tid & 63;
    const int i = blockIdx.x * 64 + il;
    if (i >= K_N) return;
    float4 bi = obox[i];
    float ai = oarea[i];
#pragma unroll
    for (int p = 0; p < 4; ++p) {
        int w = (tid >> 6) + p * 4;
        u64 word = 0ull;
        for (int jj = 0; jj < 64; ++jj) {
            int j = w * 64 + jj;
            if (j < K_N && j != i) {
                float4 bj = obox[j];
                float lx = fmaxf(bi.x, bj.x);
                float ly = fmaxf(bi.y, bj.y);
                float rx = fminf(bi.z, bj.z);
                float ry = fminf(bi.w, bj.w);
                float wx = fmaxf(rx - lx, 0.0f);
                float wy = fmaxf(ry - ly, 0.0f);
                float inter = wx * wy;
                float uni = ai + oarea[j] - inter;
                float den = fmaxf(uni, 1e-9f);
                float iou = inter / den;
                if (iou > 0.5f) word |= (1ull << jj);
            }
        }
        maskT[((size_t)b * 16 + w) * 1024 + i] = word;
    }
}

// ---------------------------------------------------------------- kernel 5
// greedy NMS scan. Diagonal 64x64 block in scalar registers via readlane;
// pure-SALU pend chain; final pend == keep set.
__global__ void __launch_bounds__(1024)
k5_scan(const u64* __restrict__ maskT,
        const float* __restrict__ topv,
        const float4* __restrict__ boxesws,
        float* __restrict__ out)
{
    const int b = blockIdx.x;
    const int t = threadIdx.x;
    const int lane = t & 63;
    const int wv = t >> 6;              // wave id == chunk id

    __shared__ u64 keeparr[16];

    const u64* mt = maskT + (size_t)b * 16 * 1024;
    const float* tv = topv + (size_t)b * K_N;

    const bool inr = t < K_N;
    const float myv = tv[inr ? t : 0];
    const bool valid = inr && (myv >= 0.5f);
    bool suppressed = false;

    u64 wcur = inr ? mt[t] : 0ull;      // my row's word 0 (coalesced)

#pragma unroll 1
    for (int d = 0; d < 16; ++d) {
        u64 wnext = 0ull;
        if (d < 15 && inr) wnext = mt[(size_t)(d + 1) * 1024 + t];  // prefetch
        if (wv == d) {
            unsigned wlo = (unsigned)wcur, whi = (unsigned)(wcur >> 32);
            u64 pend = __ballot(valid && !suppressed);
#pragma unroll
            for (int r = 0; r < 64; ++r) {
                u64 roww = ((u64)(unsigned)__builtin_amdgcn_readlane(whi, r) << 32)
                         |  (u64)(unsigned)__builtin_amdgcn_readlane(wlo, r);
                u64 take = ((pend >> r) & 1ull) ? roww : 0ull;
                pend &= ~take;
            }
            if (lane == 0) keeparr[d] = pend;   // pend == keep set for chunk d
        }
        __syncthreads();
        if (wcur & keeparr[d]) suppressed = true;
        wcur = wnext;
    }

    // outputs: boxes*keep, scores*keep, keep
    float* out_boxes  = out + (size_t)B_N * K_N;          // 32000
    float* out_scores = out + (size_t)6 * B_N * K_N;      // 192000
    float* out_keep   = out + (size_t)7 * B_N * K_N;      // 224000
    if (inr) {
        float kf = ((keeparr[wv] >> lane) & 1ull) ? 1.0f : 0.0f;
        float4 bx = boxesws[(size_t)b * K_N + t];
        size_t o = (size_t)b * K_N + t;
        out_boxes[o * 4 + 0] = bx.x * kf;
        out_boxes[o * 4 + 1] = bx.y * kf;
        out_boxes[o * 4 + 2] = bx.z * kf;
        out_boxes[o * 4 + 3] = bx.w * kf;
        out_scores[o] = myv * kf;
        out_keep[o] = kf;
    }
}

// ---------------------------------------------------------------- launch
extern "C" void kernel_launch(void* const* d_in, const int* in_sizes, int n_in,
                              void* d_out, int out_size, void* d_ws, size_t ws_size,
                              hipStream_t stream)
{
    const float* ptxywh  = (const float*)d_in[0];
    const float* pcls    = (const float*)d_in[1];
    const float* anchors = (const float*)d_in[2];
    float* out = (float*)d_out;

    char* ws = (char*)d_ws;
    size_t o = 0;
    float* pscore = (float*)(ws + o);        o += (size_t)B_N * A_N * 4;        // 4.16 MB
    u64* winuns   = (u64*)(ws + o);          o += (size_t)B_N * CAND_MAX * 8;   // 8.39 MB
    unsigned* ncand = (unsigned*)(ws + o);   o += 256;
    float* topv = (float*)(ws + o);          o += (size_t)B_N * K_N * 4;
    float4* boxesws = (float4*)(ws + o);     o += (size_t)B_N * K_N * 16;
    int* labelsws   = (int*)(ws + o);        o += (size_t)B_N * K_N * 4;
    u64* maskT = (u64*)(ws + o);             o += (size_t)B_N * 16 * 1024 * 8;  // 4.19 MB

    int total = B_N * A_N;
    k1_score<<<2048, 256, 0, stream>>>(pcls, pscore, total);
    k2_select<<<B_N, 1024, 0, stream>>>(pscore, winuns, ncand);
    k2c_rank_decode<<<dim3(8, B_N), 1024, 0, stream>>>(winuns, ncand, ptxywh, pcls,
                                                       anchors, topv, boxesws,
                                                       labelsws, out);
    k4_mask<<<dim3(16, B_N), 256, 0, stream>>>(boxesws, labelsws, maskT);
    k5_scan<<<B_N, 1024, 0, stream>>>(maskT, topv, boxesws, out);
}

// Round 7
// 127.539 us; speedup vs baseline: 1.4727x; 1.0719x over previous
//
#include <hip/hip_runtime.h>
#include <hip/hip_bf16.h>

#pragma clang fp contract(off)

#define B_N 32
#define A_N 32526
#define C_N 20
#define K_N 1000
#define CAND_MAX 32768   // worst case: all scores equal -> all candidates

typedef unsigned long long u64;

// ---------------------------------------------------------------- kernel 1
// pscore[b,a] = sigmoid(max_c logits)  (sigmoid monotone => max commutes)
__global__ void k1_score(const float* __restrict__ pcls,
                         float* __restrict__ pscore, int total)
{
    int stride = gridDim.x * blockDim.x;
    for (int t = blockIdx.x * blockDim.x + threadIdx.x; t < total; t += stride) {
        const float4* p = (const float4*)(pcls + (size_t)t * C_N);
        float m = -INFINITY;
#pragma unroll
        for (int q = 0; q < 5; ++q) {
            float4 v = p[q];
            m = fmaxf(m, fmaxf(fmaxf(v.x, v.y), fmaxf(v.z, v.w)));
        }
        double e = exp(-(double)m);     // correctly-rounded f32 sigmoid path
        pscore[t] = (float)(1.0 / (1.0 + e));
    }
}

// ---------------------------------------------------------------- kernel 2
// per batch: V = exact 1000th-largest score VALUE (15 packed 2-bit rounds,
// 1 barrier each); compact all keys with score >= V.
__global__ void __launch_bounds__(1024)
k2_select(const float* __restrict__ pscore,
          u64* __restrict__ winuns, unsigned* __restrict__ ncand)
{
    const int b = blockIdx.x;
    const int tid = threadIdx.x, lane = tid & 63, wv = tid >> 6;
    __shared__ u64 wsum[2][16];
    __shared__ unsigned cnt_s;
    if (tid == 0) cnt_s = 0;

    const float* ps = pscore + (size_t)b * A_N;
    unsigned key[32];                        // coalesced: a = tid + i*1024
#pragma unroll
    for (int i = 0; i < 32; ++i) {
        int a = tid + i * 1024;
        key[i] = (a < A_N) ? __float_as_uint(ps[a]) : 0u;
    }

    int slot = 0;
    auto bs3 = [&](unsigned a, unsigned b2, unsigned c) -> u64 {
        u64 s = (u64)a | ((u64)b2 << 21) | ((u64)c << 42);
#pragma unroll
        for (int off = 32; off > 0; off >>= 1) s += __shfl_down(s, off);
        if (lane == 0) wsum[slot][wv] = s;
        __syncthreads();
        u64 t = 0;
#pragma unroll
        for (int w = 0; w < 16; ++w) t += wsum[slot][w];
        slot ^= 1;
        return t;
    };

    // value descent over bits 29..0 (score bits <= 0x3F800000 < 2^30)
    unsigned V = 0;
#pragma unroll 1
    for (int sh = 28; sh >= 0; sh -= 2) {
        unsigned X1 = V | (1u << sh), X2 = V | (2u << sh), X3 = V | (3u << sh);
        unsigned c1 = 0, c2 = 0, c3 = 0;
#pragma unroll
        for (int i = 0; i < 32; ++i) {
            unsigned k = key[i];
            c1 += (k >= X1); c2 += (k >= X2); c3 += (k >= X3);
        }
        u64 s = bs3(c1, c2, c3);
        unsigned s1 = (unsigned)(s & 0x1FFFFFu);
        unsigned s2 = (unsigned)((s >> 21) & 0x1FFFFFu);
        unsigned s3 = (unsigned)(s >> 42);
        if (s3 >= K_N) V = X3; else if (s2 >= K_N) V = X2; else if (s1 >= K_N) V = X1;
    }

    // compact candidates (score >= V)
    u64* wb = winuns + (size_t)b * CAND_MAX;
#pragma unroll
    for (int i = 0; i < 32; ++i) {
        int a = tid + i * 1024;
        bool win = (a < A_N) && (key[i] >= V);
        u64 wm = __ballot(win);
        unsigned base = 0;
        if (lane == 0 && wm) base = atomicAdd(&cnt_s, (unsigned)__popcll(wm));
        base = __shfl(base, 0);
        if (win)
            wb[base + (unsigned)__popcll(wm & ((1ull << lane) - 1ull))] =
                ((u64)key[i] << 32) | (u64)(0xFFFFFFFFu - (unsigned)a);
    }
    __syncthreads();
    if (tid == 0) ncand[b] = cnt_s;
}

// ---------------------------------------------------------------- kernel 2c
// rank candidates by full unique key; ranks < 1000 also decode (fused k3).
__global__ void __launch_bounds__(1024)
k2c_rank_decode(const u64* __restrict__ winuns, const unsigned* __restrict__ ncand,
                const float* __restrict__ ptxywh,
                const float* __restrict__ pcls,
                const float* __restrict__ anchors,
                float* __restrict__ topv,
                float4* __restrict__ boxesws,
                int* __restrict__ labelsws,
                float* __restrict__ out)
{
    const int bc = blockIdx.x;   // 0..7
    const int b = blockIdx.y;
    const int tid = threadIdx.x;
    __shared__ u64 chunk[1024];
    const unsigned n = ncand[b];
    const u64* wb = winuns + (size_t)b * CAND_MAX;

    const int wl = tid >> 3;     // winner slot within pass: 0..127
    const int seg = tid & 7;

    for (unsigned w0 = bc * 128u; w0 < n; w0 += 1024u) {
        unsigned w = w0 + (unsigned)wl;
        bool act = (w < n);
        u64 myk = act ? wb[w] : 0ull;
        unsigned cnt = 0;
        for (unsigned j0 = 0; j0 < n; j0 += 1024u) {
            __syncthreads();
            unsigned j = j0 + tid;
            chunk[tid] = (j < n) ? wb[j] : 0ull;   // pad 0: never > myk
            __syncthreads();
#pragma unroll 16
            for (int jj = 0; jj < 128; ++jj)
                cnt += (chunk[jj * 8 + seg] > myk);
        }
        cnt += __shfl_xor(cnt, 1);
        cnt += __shfl_xor(cnt, 2);
        cnt += __shfl_xor(cnt, 4);
        if (act && seg == 0 && cnt < K_N) {
            unsigned rank = cnt;
            int a = (int)(0xFFFFFFFFu - (unsigned)(myk & 0xFFFFFFFFull));
            size_t t = (size_t)b * K_N + rank;
            topv[t] = __uint_as_float((unsigned)(myk >> 32));

            // ---- fused decode (exact former-k3 math) ----
            float4 tb = ((const float4*)ptxywh)[(size_t)b * A_N + a];
            float4 an = ((const float4*)anchors)[a];
            float xx = an.x + (tb.x * 0.1f) * an.z;
            float yy = an.y + (tb.y * 0.1f) * an.w;
            float ww = an.z * (float)exp((double)(tb.z * 0.2f));
            float hh = an.w * (float)exp((double)(tb.w * 0.2f));
            float hw = ww * 0.5f, hh2 = hh * 0.5f;
            boxesws[t] = make_float4(xx - hw, yy - hh2, xx + hw, yy + hh2);

            const float4* pc = (const float4*)(pcls + ((size_t)b * A_N + a) * C_N);
            float m = -INFINITY; int lab = 0;
#pragma unroll
            for (int q = 0; q < 5; ++q) {
                float4 v = pc[q];
                if (v.x > m) { m = v.x; lab = q * 4 + 0; }
                if (v.y > m) { m = v.y; lab = q * 4 + 1; }
                if (v.z > m) { m = v.z; lab = q * 4 + 2; }
                if (v.w > m) { m = v.w; lab = q * 4 + 3; }
            }
            labelsws[t] = lab + 1;

            out[t] = (float)b;                          // ids_batch
            out[5 * B_N * K_N + t] = (float)(lab + 1);  // labels
        }
    }
}

// ---------------------------------------------------------------- kernel 4p
// stable class-grouping permutation of the 1000 ranked rows (counting rank
// via per-wave per-class ballots). perm[pos] = original rank.
__global__ void __launch_bounds__(1024)
k4perm(const int* __restrict__ labelsws, unsigned short* __restrict__ perm)
{
    const int b = blockIdx.x;
    const int t = threadIdx.x;
    const int lane = t & 63, wv = t >> 6;
    __shared__ u64 wmask[16][21];
    __shared__ unsigned totals[21];
    __shared__ unsigned base[21];

    const bool inr = t < K_N;
    int lab = inr ? labelsws[(size_t)b * K_N + t] : 0;   // 1..20; pad=0
#pragma unroll 1
    for (int c = 1; c <= 20; ++c) {
        u64 m = __ballot(inr && lab == c);
        if (lane == 0) wmask[wv][c] = m;
    }
    __syncthreads();
    if (t >= 1 && t <= 20) {
        unsigned s = 0;
#pragma unroll
        for (int w = 0; w < 16; ++w) s += (unsigned)__popcll(wmask[w][t]);
        totals[t] = s;
    }
    __syncthreads();
    if (t == 0) {
        unsigned acc = 0;
        for (int c = 1; c <= 20; ++c) { base[c - 1] = acc; acc += totals[c]; }
    }
    __syncthreads();
    if (inr) {
        unsigned cnt = 0;
#pragma unroll 1
        for (int w = 0; w < wv; ++w) cnt += (unsigned)__popcll(wmask[w][lab]);
        cnt += (unsigned)__popcll(wmask[wv][lab] & ((1ull << lane) - 1ull));
        perm[(size_t)b * K_N + base[lab - 1] + cnt] = (unsigned short)t;
    }
}

// ---------------------------------------------------------------- kernel 4
// suppression bitmask, TRANSPOSED layout: maskT[(b*16 + w)*1024 + i].
// Rows are processed in class-sorted order (perm) so the different-label
// skip (iou == 0 exactly: class offset 10 >> max box extent) is
// wave-coherent; mask is still indexed by ORIGINAL rank i.
__global__ void k4_mask(const float4* __restrict__ boxesws,
                        const int* __restrict__ labelsws,
                        const unsigned short* __restrict__ perm,
                        u64* __restrict__ maskT)
{
    const int b = blockIdx.y;
    const int tid = threadIdx.x;
    __shared__ float4 obox[K_N];
    __shared__ float oarea[K_N];
    __shared__ int olab[K_N];

    for (int idx = tid; idx < K_N; idx += 256) {
        float4 bx = boxesws[(size_t)b * K_N + idx];
        int lb = labelsws[(size_t)b * K_N + idx];
        float off = (float)lb * 10.0f;
        float l = bx.x + off, t2 = bx.y + off, r = bx.z + off, bo = bx.w + off;
        obox[idx] = make_float4(l, t2, r, bo);
        oarea[idx] = (r - l) * (bo - t2);
        olab[idx] = lb;
    }
    __syncthreads();

    const int il = tid & 63;
    const int pi = blockIdx.x * 64 + il;       // class-sorted slot
    if (pi >= K_N) return;
    const int i = perm[(size_t)b * K_N + pi];  // original rank
    float4 bi = obox[i];
    float ai = oarea[i];
    int li = olab[i];
#pragma unroll
    for (int p = 0; p < 4; ++p) {
        int w = (tid >> 6) + p * 4;
        u64 word = 0ull;
        for (int jj = 0; jj < 64; ++jj) {
            int j = w * 64 + jj;
            if (j < K_N && olab[j] == li && j != i) {
                float4 bj = obox[j];
                float lx = fmaxf(bi.x, bj.x);
                float ly = fmaxf(bi.y, bj.y);
                float rx = fminf(bi.z, bj.z);
                float ry = fminf(bi.w, bj.w);
                float wx = fmaxf(rx - lx, 0.0f);
                float wy = fmaxf(ry - ly, 0.0f);
                float inter = wx * wy;
                float uni = ai + oarea[j] - inter;
                float den = fmaxf(uni, 1e-9f);
                float iou = inter / den;
                if (iou > 0.5f) word |= (1ull << jj);
            }
        }
        maskT[((size_t)b * 16 + w) * 1024 + i] = word;
    }
}

// ---------------------------------------------------------------- kernel 5
// greedy NMS scan. Diagonal 64x64 block in scalar registers via readlane;
// pure-SALU pend chain; final pend == keep set.
__global__ void __launch_bounds__(1024)
k5_scan(const u64* __restrict__ maskT,
        const float* __restrict__ topv,
        const float4* __restrict__ boxesws,
        float* __restrict__ out)
{
    const int b = blockIdx.x;
    const int t = threadIdx.x;
    const int lane = t & 63;
    const int wv = t >> 6;              // wave id == chunk id

    __shared__ u64 keeparr[16];

    const u64* mt = maskT + (size_t)b * 16 * 1024;
    const float* tv = topv + (size_t)b * K_N;

    const bool inr = t < K_N;
    const float myv = tv[inr ? t : 0];
    const bool valid = inr && (myv >= 0.5f);
    bool suppressed = false;

    u64 wcur = inr ? mt[t] : 0ull;      // my row's word 0 (coalesced)

#pragma unroll 1
    for (int d = 0; d < 16; ++d) {
        u64 wnext = 0ull;
        if (d < 15 && inr) wnext = mt[(size_t)(d + 1) * 1024 + t];  // prefetch
        if (wv == d) {
            unsigned wlo = (unsigned)wcur, whi = (unsigned)(wcur >> 32);
            u64 pend = __ballot(valid && !suppressed);
#pragma unroll
            for (int r = 0; r < 64; ++r) {
                u64 roww = ((u64)(unsigned)__builtin_amdgcn_readlane(whi, r) << 32)
                         |  (u64)(unsigned)__builtin_amdgcn_readlane(wlo, r);
                u64 take = ((pend >> r) & 1ull) ? roww : 0ull;
                pend &= ~take;
            }
            if (lane == 0) keeparr[d] = pend;   // pend == keep set for chunk d
        }
        __syncthreads();
        if (wcur & keeparr[d]) suppressed = true;
        wcur = wnext;
    }

    // outputs: boxes*keep, scores*keep, keep
    float* out_boxes  = out + (size_t)B_N * K_N;          // 32000
    float* out_scores = out + (size_t)6 * B_N * K_N;      // 192000
    float* out_keep   = out + (size_t)7 * B_N * K_N;      // 224000
    if (inr) {
        float kf = ((keeparr[wv] >> lane) & 1ull) ? 1.0f : 0.0f;
        float4 bx = boxesws[(size_t)b * K_N + t];
        size_t o = (size_t)b * K_N + t;
        out_boxes[o * 4 + 0] = bx.x * kf;
        out_boxes[o * 4 + 1] = bx.y * kf;
        out_boxes[o * 4 + 2] = bx.z * kf;
        out_boxes[o * 4 + 3] = bx.w * kf;
        out_scores[o] = myv * kf;
        out_keep[o] = kf;
    }
}

// ---------------------------------------------------------------- launch
extern "C" void kernel_launch(void* const* d_in, const int* in_sizes, int n_in,
                              void* d_out, int out_size, void* d_ws, size_t ws_size,
                              hipStream_t stream)
{
    const float* ptxywh  = (const float*)d_in[0];
    const float* pcls    = (const float*)d_in[1];
    const float* anchors = (const float*)d_in[2];
    float* out = (float*)d_out;

    char* ws = (char*)d_ws;
    size_t o = 0;
    float* pscore = (float*)(ws + o);        o += (size_t)B_N * A_N * 4;        // 4.16 MB
    u64* winuns   = (u64*)(ws + o);          o += (size_t)B_N * CAND_MAX * 8;   // 8.39 MB
    unsigned* ncand = (unsigned*)(ws + o);   o += 256;
    float* topv = (float*)(ws + o);          o += (size_t)B_N * K_N * 4;
    float4* boxesws = (float4*)(ws + o);     o += (size_t)B_N * K_N * 16;
    int* labelsws   = (int*)(ws + o);        o += (size_t)B_N * K_N * 4;
    unsigned short* perm = (unsigned short*)(ws + o); o += (size_t)B_N * K_N * 2;
    o = (o + 255) & ~(size_t)255;
    u64* maskT = (u64*)(ws + o);             o += (size_t)B_N * 16 * 1024 * 8;  // 4.19 MB

    int total = B_N * A_N;
    k1_score<<<2048, 256, 0, stream>>>(pcls, pscore, total);
    k2_select<<<B_N, 1024, 0, stream>>>(pscore, winuns, ncand);
    k2c_rank_decode<<<dim3(8, B_N), 1024, 0, stream>>>(winuns, ncand, ptxywh, pcls,
                                                       anchors, topv, boxesws,
                                                       labelsws, out);
    k4perm<<<B_N, 1024, 0, stream>>>(labelsws, perm);
    k4_mask<<<dim3(16, B_N), 256, 0, stream>>>(boxesws, labelsws, perm, maskT);
    k5_scan<<<B_N, 1024, 0, stream>>>(maskT, topv, boxesws, out);
}

// Round 8
// 90.252 us; speedup vs baseline: 2.0812x; 1.4131x over previous
//
#include <hip/hip_runtime.h>
#include <hip/hip_bf16.h>

#pragma clang fp contract(off)

#define B_N 32
#define A_N 32526
#define C_N 20
#define K_N 1000
#define CAND_MAX 32768   // worst case: all scores equal -> all candidates

typedef unsigned long long u64;

// ---------------------------------------------------------------- kernel 1
// pscore[b,a] = sigmoid(max_c logits)  (sigmoid monotone => max commutes)
__global__ void k1_score(const float* __restrict__ pcls,
                         float* __restrict__ pscore, int total)
{
    int stride = gridDim.x * blockDim.x;
    for (int t = blockIdx.x * blockDim.x + threadIdx.x; t < total; t += stride) {
        const float4* p = (const float4*)(pcls + (size_t)t * C_N);
        float m = -INFINITY;
#pragma unroll
        for (int q = 0; q < 5; ++q) {
            float4 v = p[q];
            m = fmaxf(m, fmaxf(fmaxf(v.x, v.y), fmaxf(v.z, v.w)));
        }
        double e = exp(-(double)m);     // correctly-rounded f32 sigmoid path
        pscore[t] = (float)(1.0 / (1.0 + e));
    }
}

// ---------------------------------------------------------------- kernel 2
// per batch: V = exact 1000th-largest score VALUE (15 packed 2-bit rounds,
// 1 barrier each); compact all keys with score >= V.
__global__ void __launch_bounds__(1024)
k2_select(const float* __restrict__ pscore,
          u64* __restrict__ winuns, unsigned* __restrict__ ncand)
{
    const int b = blockIdx.x;
    const int tid = threadIdx.x, lane = tid & 63, wv = tid >> 6;
    __shared__ u64 wsum[2][16];
    __shared__ unsigned cnt_s;
    if (tid == 0) cnt_s = 0;

    const float* ps = pscore + (size_t)b * A_N;
    unsigned key[32];                        // coalesced: a = tid + i*1024
#pragma unroll
    for (int i = 0; i < 32; ++i) {
        int a = tid + i * 1024;
        key[i] = (a < A_N) ? __float_as_uint(ps[a]) : 0u;
    }

    int slot = 0;
    auto bs3 = [&](unsigned a, unsigned b2, unsigned c) -> u64 {
        u64 s = (u64)a | ((u64)b2 << 21) | ((u64)c << 42);
#pragma unroll
        for (int off = 32; off > 0; off >>= 1) s += __shfl_down(s, off);
        if (lane == 0) wsum[slot][wv] = s;
        __syncthreads();
        u64 t = 0;
#pragma unroll
        for (int w = 0; w < 16; ++w) t += wsum[slot][w];
        slot ^= 1;
        return t;
    };

    // value descent over bits 29..0 (score bits <= 0x3F800000 < 2^30)
    unsigned V = 0;
#pragma unroll 1
    for (int sh = 28; sh >= 0; sh -= 2) {
        unsigned X1 = V | (1u << sh), X2 = V | (2u << sh), X3 = V | (3u << sh);
        unsigned c1 = 0, c2 = 0, c3 = 0;
#pragma unroll
        for (int i = 0; i < 32; ++i) {
            unsigned k = key[i];
            c1 += (k >= X1); c2 += (k >= X2); c3 += (k >= X3);
        }
        u64 s = bs3(c1, c2, c3);
        unsigned s1 = (unsigned)(s & 0x1FFFFFu);
        unsigned s2 = (unsigned)((s >> 21) & 0x1FFFFFu);
        unsigned s3 = (unsigned)(s >> 42);
        if (s3 >= K_N) V = X3; else if (s2 >= K_N) V = X2; else if (s1 >= K_N) V = X1;
    }

    // compact candidates (score >= V)
    u64* wb = winuns + (size_t)b * CAND_MAX;
#pragma unroll
    for (int i = 0; i < 32; ++i) {
        int a = tid + i * 1024;
        bool win = (a < A_N) && (key[i] >= V);
        u64 wm = __ballot(win);
        unsigned base = 0;
        if (lane == 0 && wm) base = atomicAdd(&cnt_s, (unsigned)__popcll(wm));
        base = __shfl(base, 0);
        if (win)
            wb[base + (unsigned)__popcll(wm & ((1ull << lane) - 1ull))] =
                ((u64)key[i] << 32) | (u64)(0xFFFFFFFFu - (unsigned)a);
    }
    __syncthreads();
    if (tid == 0) ncand[b] = cnt_s;
}

// ---------------------------------------------------------------- kernel 2c
// rank candidates by full unique key; ranks < 1000 also decode (fused k3).
__global__ void __launch_bounds__(1024)
k2c_rank_decode(const u64* __restrict__ winuns, const unsigned* __restrict__ ncand,
                const float* __restrict__ ptxywh,
                const float* __restrict__ pcls,
                const float* __restrict__ anchors,
                float* __restrict__ topv,
                float4* __restrict__ boxesws,
                int* __restrict__ labelsws,
                float* __restrict__ out)
{
    const int bc = blockIdx.x;   // 0..7
    const int b = blockIdx.y;
    const int tid = threadIdx.x;
    __shared__ u64 chunk[1024];
    const unsigned n = ncand[b];
    const u64* wb = winuns + (size_t)b * CAND_MAX;

    const int wl = tid >> 3;     // winner slot within pass: 0..127
    const int seg = tid & 7;

    for (unsigned w0 = bc * 128u; w0 < n; w0 += 1024u) {
        unsigned w = w0 + (unsigned)wl;
        bool act = (w < n);
        u64 myk = act ? wb[w] : 0ull;
        unsigned cnt = 0;
        for (unsigned j0 = 0; j0 < n; j0 += 1024u) {
            __syncthreads();
            unsigned j = j0 + tid;
            chunk[tid] = (j < n) ? wb[j] : 0ull;   // pad 0: never > myk
            __syncthreads();
#pragma unroll 16
            for (int jj = 0; jj < 128; ++jj)
                cnt += (chunk[jj * 8 + seg] > myk);
        }
        cnt += __shfl_xor(cnt, 1);
        cnt += __shfl_xor(cnt, 2);
        cnt += __shfl_xor(cnt, 4);
        if (act && seg == 0 && cnt < K_N) {
            unsigned rank = cnt;
            int a = (int)(0xFFFFFFFFu - (unsigned)(myk & 0xFFFFFFFFull));
            size_t t = (size_t)b * K_N + rank;
            topv[t] = __uint_as_float((unsigned)(myk >> 32));

            // ---- fused decode (exact former-k3 math) ----
            float4 tb = ((const float4*)ptxywh)[(size_t)b * A_N + a];
            float4 an = ((const float4*)anchors)[a];
            float xx = an.x + (tb.x * 0.1f) * an.z;
            float yy = an.y + (tb.y * 0.1f) * an.w;
            float ww = an.z * (float)exp((double)(tb.z * 0.2f));
            float hh = an.w * (float)exp((double)(tb.w * 0.2f));
            float hw = ww * 0.5f, hh2 = hh * 0.5f;
            boxesws[t] = make_float4(xx - hw, yy - hh2, xx + hw, yy + hh2);

            const float4* pc = (const float4*)(pcls + ((size_t)b * A_N + a) * C_N);
            float m = -INFINITY; int lab = 0;
#pragma unroll
            for (int q = 0; q < 5; ++q) {
                float4 v = pc[q];
                if (v.x > m) { m = v.x; lab = q * 4 + 0; }
                if (v.y > m) { m = v.y; lab = q * 4 + 1; }
                if (v.z > m) { m = v.z; lab = q * 4 + 2; }
                if (v.w > m) { m = v.w; lab = q * 4 + 3; }
            }
            labelsws[t] = lab + 1;

            out[t] = (float)b;                          // ids_batch
            out[5 * B_N * K_N + t] = (float)(lab + 1);  // labels
        }
    }
}

// ---------------------------------------------------------------- kernel 45
// per-(batch, class) greedy NMS. Cross-class IoU is exactly 0 (class offset
// 10 >> max box extent ~3.2, so rb-lt < 0 -> clip 0 -> inter 0), and the
// stable class grouping preserves rank order within a class, so per-class
// greedy in class-rank order is bit-identical to the reference's global
// 1000-step greedy. One wave per (b, class); on-the-fly IoU; kept boxes
// accumulate in LDS for cross-chunk (n_c > 64) suppression.
__global__ void __launch_bounds__(64)
k45_nms(const float* __restrict__ topv,
        const float4* __restrict__ boxesws,
        const int* __restrict__ labelsws,
        float* __restrict__ out)
{
    const int c = blockIdx.x + 1;       // class 1..20
    const int b = blockIdx.y;
    const int lane = threadIdx.x;       // 64 threads = 1 wave

    __shared__ unsigned short mem[K_N];
    __shared__ float keptL[K_N], keptT[K_N], keptR[K_N], keptB[K_N], keptA[K_N];

    const int*    labs = labelsws + (size_t)b * K_N;
    const float*  tv   = topv     + (size_t)b * K_N;
    const float4* bw   = boxesws  + (size_t)b * K_N;

    // gather this class's members in rank order (stable ballot compaction)
    unsigned nmem = 0;
#pragma unroll 1
    for (int r0 = 0; r0 < K_N; r0 += 64) {
        int r = r0 + lane;
        bool is = (r < K_N) && (labs[r] == c);
        u64 bm = __ballot(is);
        if (is) mem[nmem + (unsigned)__popcll(bm & ((1ull << lane) - 1ull))] =
                    (unsigned short)r;
        nmem += (unsigned)__popcll(bm);
    }
    __syncthreads();

    const float off = (float)c * 10.0f;
    unsigned nkept = 0;

    float* out_boxes  = out + (size_t)B_N * K_N;          // 32000
    float* out_scores = out + (size_t)6 * B_N * K_N;      // 192000
    float* out_keep   = out + (size_t)7 * B_N * K_N;      // 224000

#pragma unroll 1
    for (unsigned q0 = 0; q0 < nmem; q0 += 64) {
        unsigned midx = q0 + (unsigned)lane;
        bool act = midx < nmem;
        int r = act ? (int)mem[midx] : 0;
        float4 bx = bw[r];
        // offset box + area, exact reference op order
        float l  = bx.x + off, t = bx.y + off;
        float rr = bx.z + off, bb = bx.w + off;
        float area = (rr - l) * (bb - t);
        float sc = tv[r];
        bool valid = act && (sc >= 0.5f);

        // suppression by earlier-chunk kept boxes
        bool supp = false;
#pragma unroll 1
        for (unsigned k = 0; k < nkept; ++k) {
            float lx = fmaxf(keptL[k], l);
            float ly = fmaxf(keptT[k], t);
            float rx = fminf(keptR[k], rr);
            float ry = fminf(keptB[k], bb);
            float wx = fmaxf(rx - lx, 0.0f);
            float wy = fmaxf(ry - ly, 0.0f);
            float inter = wx * wy;
            float uni = keptA[k] + area - inter;
            float iou = inter / fmaxf(uni, 1e-9f);
            supp |= (iou > 0.5f);
        }

        // intra-chunk greedy, class-rank order, on-the-fly IoU
        u64 todo = __ballot(valid && !supp);
        u64 keepw = 0ull;
        while (todo) {
            int i = (int)__builtin_ctzll(todo);
            todo &= todo - 1ull;
            keepw |= (1ull << i);
            float bl = __shfl(l, i),  bt  = __shfl(t, i);
            float br = __shfl(rr, i), bbo = __shfl(bb, i);
            float ba = __shfl(area, i);
            float lx = fmaxf(bl, l),  ly = fmaxf(bt, t);
            float rx = fminf(br, rr), ry = fminf(bbo, bb);
            float wx = fmaxf(rx - lx, 0.0f), wy = fmaxf(ry - ly, 0.0f);
            float inter = wx * wy;
            float uni = ba + area - inter;
            float iou = inter / fmaxf(uni, 1e-9f);
            u64 sm = __ballot((iou > 0.5f) && (lane != i));
            todo &= ~sm;
        }

        // append kept boxes to LDS list
        if ((keepw >> lane) & 1ull) {
            unsigned ki = nkept + (unsigned)__popcll(keepw & ((1ull << lane) - 1ull));
            keptL[ki] = l; keptT[ki] = t; keptR[ki] = rr;
            keptB[ki] = bb; keptA[ki] = area;
        }
        nkept += (unsigned)__popcll(keepw);
        __syncthreads();

        // outputs for my member (class blocks partition the 1000 ranks)
        if (act) {
            float kf = ((keepw >> lane) & 1ull) ? 1.0f : 0.0f;
            size_t o = (size_t)b * K_N + r;
            out_boxes[o * 4 + 0] = bx.x * kf;
            out_boxes[o * 4 + 1] = bx.y * kf;
            out_boxes[o * 4 + 2] = bx.z * kf;
            out_boxes[o * 4 + 3] = bx.w * kf;
            out_scores[o] = sc * kf;
            out_keep[o] = kf;
        }
    }
}

// ---------------------------------------------------------------- launch
extern "C" void kernel_launch(void* const* d_in, const int* in_sizes, int n_in,
                              void* d_out, int out_size, void* d_ws, size_t ws_size,
                              hipStream_t stream)
{
    const float* ptxywh  = (const float*)d_in[0];
    const float* pcls    = (const float*)d_in[1];
    const float* anchors = (const float*)d_in[2];
    float* out = (float*)d_out;

    char* ws = (char*)d_ws;
    size_t o = 0;
    float* pscore = (float*)(ws + o);        o += (size_t)B_N * A_N * 4;        // 4.16 MB
    u64* winuns   = (u64*)(ws + o);          o += (size_t)B_N * CAND_MAX * 8;   // 8.39 MB
    unsigned* ncand = (unsigned*)(ws + o);   o += 256;
    float* topv = (float*)(ws + o);          o += (size_t)B_N * K_N * 4;
    float4* boxesws = (float4*)(ws + o);     o += (size_t)B_N * K_N * 16;
    int* labelsws   = (int*)(ws + o);        o += (size_t)B_N * K_N * 4;

    int total = B_N * A_N;
    k1_score<<<2048, 256, 0, stream>>>(pcls, pscore, total);
    k2_select<<<B_N, 1024, 0, stream>>>(pscore, winuns, ncand);
    k2c_rank_decode<<<dim3(8, B_N), 1024, 0, stream>>>(winuns, ncand, ptxywh, pcls,
                                                       anchors, topv, boxesws,
                                                       labelsws, out);
    k45_nms<<<dim3(20, B_N), 64, 0, stream>>>(topv, boxesws, labelsws, out);
}

// Round 9
// 75.914 us; speedup vs baseline: 2.4742x; 1.1889x over previous
//
#include <hip/hip_runtime.h>
#include <hip/hip_bf16.h>

#pragma clang fp contract(off)

#define B_N 32
#define A_N 32526
#define C_N 20
#define K_N 1000
#define CAND_MAX 32768   // worst case: all scores equal -> all candidates
#define LIVE_MAX 4096    // LDS live-set capacity for the fast descent path

typedef unsigned long long u64;

// ---------------------------------------------------------------- kernel 1
// pscore[b,a] = sigmoid(max_c logits)  (sigmoid monotone => max commutes)
__global__ void k1_score(const float* __restrict__ pcls,
                         float* __restrict__ pscore, int total)
{
    int stride = gridDim.x * blockDim.x;
    for (int t = blockIdx.x * blockDim.x + threadIdx.x; t < total; t += stride) {
        const float4* p = (const float4*)(pcls + (size_t)t * C_N);
        float m = -INFINITY;
#pragma unroll
        for (int q = 0; q < 5; ++q) {
            float4 v = p[q];
            m = fmaxf(m, fmaxf(fmaxf(v.x, v.y), fmaxf(v.z, v.w)));
        }
        double e = exp(-(double)m);     // correctly-rounded f32 sigmoid path
        pscore[t] = (float)(1.0 / (1.0 + e));
    }
}

// ---------------------------------------------------------------- kernel 2
// per batch: V = exact 1000th-largest score VALUE via 2-bit descent with
// adaptive live-set compaction: once live <= 4096, keys move to LDS and
// each thread keeps 4 in registers -> remaining rounds are barrier-only.
// Then compact all keys with score >= V to global (ties resolved by k2c).
__global__ void __launch_bounds__(1024)
k2_select(const float* __restrict__ pscore,
          u64* __restrict__ winuns, unsigned* __restrict__ ncand)
{
    const int b = blockIdx.x;
    const int tid = threadIdx.x, lane = tid & 63, wv = tid >> 6;
    __shared__ u64 wsum[2][16];
    __shared__ u64 lkey[LIVE_MAX];
    __shared__ unsigned cnt_s;

    const float* ps = pscore + (size_t)b * A_N;
    unsigned key[32];                        // coalesced: a = tid + i*1024
#pragma unroll
    for (int i = 0; i < 32; ++i) {
        int a = tid + i * 1024;
        key[i] = (a < A_N) ? __float_as_uint(ps[a]) : 0u;
    }

    int slot = 0;
    // block-wide 3-count packed sum; one barrier; broadcast LDS reads
    auto bs3 = [&](unsigned a, unsigned b2, unsigned c) -> u64 {
        u64 s = (u64)a | ((u64)b2 << 21) | ((u64)c << 42);
#pragma unroll
        for (int off = 32; off > 0; off >>= 1) s += __shfl_down(s, off);
        if (lane == 0) wsum[slot][wv] = s;
        __syncthreads();
        u64 t = 0;
#pragma unroll
        for (int w = 0; w < 16; ++w) t += wsum[slot][w];
        slot ^= 1;
        return t;
    };

    unsigned V = 0;
    unsigned live = A_N;
    int sh = 28;

    // phase 1: full-register rounds (32 keys/thread) while live set large
#pragma unroll 1
    while (sh >= 0 && live > LIVE_MAX) {
        unsigned X1 = V | (1u << sh), X2 = V | (2u << sh), X3 = V | (3u << sh);
        unsigned c1 = 0, c2 = 0, c3 = 0;
#pragma unroll
        for (int i = 0; i < 32; ++i) {
            unsigned k = key[i];
            c1 += (k >= X1); c2 += (k >= X2); c3 += (k >= X3);
        }
        u64 s = bs3(c1, c2, c3);
        unsigned s1 = (unsigned)(s & 0x1FFFFFu);
        unsigned s2 = (unsigned)((s >> 21) & 0x1FFFFFu);
        unsigned s3 = (unsigned)(s >> 42);
        if (s3 >= K_N)      { V = X3; live = s3; }
        else if (s2 >= K_N) { V = X2; live = s2; }
        else if (s1 >= K_N) { V = X1; live = s1; }
        sh -= 2;
    }

    u64* wb = winuns + (size_t)b * CAND_MAX;

    if (sh >= 0) {
        // ---- fast path: compact live keys (>= V) to LDS, 4 regs/thread ----
        if (tid == 0) cnt_s = 0;
        __syncthreads();
#pragma unroll
        for (int i = 0; i < 32; ++i) {
            int a = tid + i * 1024;
            bool liv = (a < A_N) && (key[i] >= V);
            u64 wm = __ballot(liv);
            unsigned base = 0;
            if (lane == 0 && wm) base = atomicAdd(&cnt_s, (unsigned)__popcll(wm));
            base = __shfl(base, 0);
            if (liv)
                lkey[base + (unsigned)__popcll(wm & ((1ull << lane) - 1ull))] =
                    ((u64)key[i] << 32) | (u64)(0xFFFFFFFFu - (unsigned)a);
        }
        __syncthreads();
        const unsigned nl = cnt_s;          // == live <= LIVE_MAX
        u64 kk0 = (tid          < nl) ? lkey[tid]          : 0ull;
        u64 kk1 = (tid + 1024u  < nl) ? lkey[tid + 1024]   : 0ull;
        u64 kk2 = (tid + 2048u  < nl) ? lkey[tid + 2048]   : 0ull;
        u64 kk3 = (tid + 3072u  < nl) ? lkey[tid + 3072]   : 0ull;

        // phase 2: barrier-floor rounds on <= 4 keys/thread
#pragma unroll 1
        while (sh >= 0) {
            u64 X1 = (u64)(V | (1u << sh)) << 32;
            u64 X2 = (u64)(V | (2u << sh)) << 32;
            u64 X3 = (u64)(V | (3u << sh)) << 32;
            unsigned c1 = (kk0 >= X1) + (kk1 >= X1) + (kk2 >= X1) + (kk3 >= X1);
            unsigned c2 = (kk0 >= X2) + (kk1 >= X2) + (kk2 >= X2) + (kk3 >= X2);
            unsigned c3 = (kk0 >= X3) + (kk1 >= X3) + (kk2 >= X3) + (kk3 >= X3);
            u64 s = bs3(c1, c2, c3);
            unsigned s1 = (unsigned)(s & 0x1FFFFFu);
            unsigned s2 = (unsigned)((s >> 21) & 0x1FFFFFu);
            unsigned s3 = (unsigned)(s >> 42);
            if (s3 >= K_N)      V = (unsigned)(X3 >> 32);
            else if (s2 >= K_N) V = (unsigned)(X2 >> 32);
            else if (s1 >= K_N) V = (unsigned)(X1 >> 32);
            sh -= 2;
        }

        // final compaction of winners (score >= V) from the 4 registers
        if (tid == 0) cnt_s = 0;
        __syncthreads();
        const u64 VV = (u64)V << 32;
        u64 kk[4] = {kk0, kk1, kk2, kk3};
#pragma unroll
        for (int i = 0; i < 4; ++i) {
            bool win = kk[i] >= VV;          // pads are 0 -> never win
            u64 wm = __ballot(win);
            unsigned base = 0;
            if (lane == 0 && wm) base = atomicAdd(&cnt_s, (unsigned)__popcll(wm));
            base = __shfl(base, 0);
            if (win)
                wb[base + (unsigned)__popcll(wm & ((1ull << lane) - 1ull))] = kk[i];
        }
        __syncthreads();
        if (tid == 0) ncand[b] = cnt_s;
    } else {
        // ---- fallback (mass ties; never hit on bench data): register path ----
        if (tid == 0) cnt_s = 0;
        __syncthreads();
#pragma unroll
        for (int i = 0; i < 32; ++i) {
            int a = tid + i * 1024;
            bool win = (a < A_N) && (key[i] >= V);
            u64 wm = __ballot(win);
            unsigned base = 0;
            if (lane == 0 && wm) base = atomicAdd(&cnt_s, (unsigned)__popcll(wm));
            base = __shfl(base, 0);
            if (win)
                wb[base + (unsigned)__popcll(wm & ((1ull << lane) - 1ull))] =
                    ((u64)key[i] << 32) | (u64)(0xFFFFFFFFu - (unsigned)a);
        }
        __syncthreads();
        if (tid == 0) ncand[b] = cnt_s;
    }
}

// ---------------------------------------------------------------- kernel 2c
// rank candidates by full unique key; ranks < 1000 also decode (fused k3).
// 8 threads/winner; pair-reads (ulonglong2) halve LDS instruction count;
// bank stride 4 across the 8 segs -> conflict-free.
__global__ void __launch_bounds__(1024)
k2c_rank_decode(const u64* __restrict__ winuns, const unsigned* __restrict__ ncand,
                const float* __restrict__ ptxywh,
                const float* __restrict__ pcls,
                const float* __restrict__ anchors,
                float* __restrict__ topv,
                float4* __restrict__ boxesws,
                int* __restrict__ labelsws,
                float* __restrict__ out)
{
    const int bc = blockIdx.x;   // 0..7
    const int b = blockIdx.y;
    const int tid = threadIdx.x;
    __shared__ u64 chunk[1024];
    const unsigned n = ncand[b];
    const u64* wb = winuns + (size_t)b * CAND_MAX;

    const int wl = tid >> 3;     // winner slot within pass: 0..127
    const int seg = tid & 7;

    for (unsigned w0 = bc * 128u; w0 < n; w0 += 1024u) {
        unsigned w = w0 + (unsigned)wl;
        bool act = (w < n);
        u64 myk = act ? wb[w] : 0ull;
        unsigned cnt = 0;
        for (unsigned j0 = 0; j0 < n; j0 += 1024u) {
            __syncthreads();
            unsigned j = j0 + tid;
            chunk[tid] = (j < n) ? wb[j] : 0ull;   // pad 0: never > myk
            __syncthreads();
            const ulonglong2* c2p = (const ulonglong2*)chunk;
#pragma unroll 16
            for (int jj = 0; jj < 64; ++jj) {
                ulonglong2 p = c2p[jj * 8 + seg];
                cnt += (p.x > myk) + (p.y > myk);
            }
        }
        cnt += __shfl_xor(cnt, 1);
        cnt += __shfl_xor(cnt, 2);
        cnt += __shfl_xor(cnt, 4);
        if (act && seg == 0 && cnt < K_N) {
            unsigned rank = cnt;
            int a = (int)(0xFFFFFFFFu - (unsigned)(myk & 0xFFFFFFFFull));
            size_t t = (size_t)b * K_N + rank;
            topv[t] = __uint_as_float((unsigned)(myk >> 32));

            // ---- fused decode (exact former-k3 math) ----
            float4 tb = ((const float4*)ptxywh)[(size_t)b * A_N + a];
            float4 an = ((const float4*)anchors)[a];
            float xx = an.x + (tb.x * 0.1f) * an.z;
            float yy = an.y + (tb.y * 0.1f) * an.w;
            float ww = an.z * (float)exp((double)(tb.z * 0.2f));
            float hh = an.w * (float)exp((double)(tb.w * 0.2f));
            float hw = ww * 0.5f, hh2 = hh * 0.5f;
            boxesws[t] = make_float4(xx - hw, yy - hh2, xx + hw, yy + hh2);

            const float4* pc = (const float4*)(pcls + ((size_t)b * A_N + a) * C_N);
            float m = -INFINITY; int lab = 0;
#pragma unroll
            for (int q = 0; q < 5; ++q) {
                float4 v = pc[q];
                if (v.x > m) { m = v.x; lab = q * 4 + 0; }
                if (v.y > m) { m = v.y; lab = q * 4 + 1; }
                if (v.z > m) { m = v.z; lab = q * 4 + 2; }
                if (v.w > m) { m = v.w; lab = q * 4 + 3; }
            }
            labelsws[t] = lab + 1;

            out[t] = (float)b;                          // ids_batch
            out[5 * B_N * K_N + t] = (float)(lab + 1);  // labels
        }
    }
}

// ---------------------------------------------------------------- kernel 45
// per-(batch, class) greedy NMS (cross-class IoU exactly 0 after +10*label
// offset; stable class grouping preserves rank order within class -> bit-
// identical to the global 1000-step greedy). One wave per (b, class).
__global__ void __launch_bounds__(64)
k45_nms(const float* __restrict__ topv,
        const float4* __restrict__ boxesws,
        const int* __restrict__ labelsws,
        float* __restrict__ out)
{
    const int c = blockIdx.x + 1;       // class 1..20
    const int b = blockIdx.y;
    const int lane = threadIdx.x;       // 64 threads = 1 wave

    __shared__ unsigned short mem[K_N];
    __shared__ float keptL[K_N], keptT[K_N], keptR[K_N], keptB[K_N], keptA[K_N];

    const int*    labs = labelsws + (size_t)b * K_N;
    const float*  tv   = topv     + (size_t)b * K_N;
    const float4* bw   = boxesws  + (size_t)b * K_N;

    // gather this class's members in rank order (stable ballot compaction)
    unsigned nmem = 0;
#pragma unroll 1
    for (int r0 = 0; r0 < K_N; r0 += 64) {
        int r = r0 + lane;
        bool is = (r < K_N) && (labs[r] == c);
        u64 bm = __ballot(is);
        if (is) mem[nmem + (unsigned)__popcll(bm & ((1ull << lane) - 1ull))] =
                    (unsigned short)r;
        nmem += (unsigned)__popcll(bm);
    }
    __syncthreads();

    const float off = (float)c * 10.0f;
    unsigned nkept = 0;

    float* out_boxes  = out + (size_t)B_N * K_N;          // 32000
    float* out_scores = out + (size_t)6 * B_N * K_N;      // 192000
    float* out_keep   = out + (size_t)7 * B_N * K_N;      // 224000

#pragma unroll 1
    for (unsigned q0 = 0; q0 < nmem; q0 += 64) {
        unsigned midx = q0 + (unsigned)lane;
        bool act = midx < nmem;
        int r = act ? (int)mem[midx] : 0;
        float4 bx = bw[r];
        // offset box + area, exact reference op order
        float l  = bx.x + off, t = bx.y + off;
        float rr = bx.z + off, bb = bx.w + off;
        float area = (rr - l) * (bb - t);
        float sc = tv[r];
        bool valid = act && (sc >= 0.5f);

        // suppression by earlier-chunk kept boxes
        bool supp = false;
#pragma unroll 1
        for (unsigned k = 0; k < nkept; ++k) {
            float lx = fmaxf(keptL[k], l);
            float ly = fmaxf(keptT[k], t);
            float rx = fminf(keptR[k], rr);
            float ry = fminf(keptB[k], bb);
            float wx = fmaxf(rx - lx, 0.0f);
            float wy = fmaxf(ry - ly, 0.0f);
            float inter = wx * wy;
            float uni = keptA[k] + area - inter;
            float iou = inter / fmaxf(uni, 1e-9f);
            supp |= (iou > 0.5f);
        }

        // intra-chunk greedy, class-rank order, on-the-fly IoU
        u64 todo = __ballot(valid && !supp);
        u64 keepw = 0ull;
        while (todo) {
            int i = (int)__builtin_ctzll(todo);
            todo &= todo - 1ull;
            keepw |= (1ull << i);
            float bl = __shfl(l, i),  bt  = __shfl(t, i);
            float br = __shfl(rr, i), bbo = __shfl(bb, i);
            float ba = __shfl(area, i);
            float lx = fmaxf(bl, l),  ly = fmaxf(bt, t);
            float rx = fminf(br, rr), ry = fminf(bbo, bb);
            float wx = fmaxf(rx - lx, 0.0f), wy = fmaxf(ry - ly, 0.0f);
            float inter = wx * wy;
            float uni = ba + area - inter;
            float iou = inter / fmaxf(uni, 1e-9f);
            u64 sm = __ballot((iou > 0.5f) && (lane != i));
            todo &= ~sm;
        }

        // append kept boxes to LDS list
        if ((keepw >> lane) & 1ull) {
            unsigned ki = nkept + (unsigned)__popcll(keepw & ((1ull << lane) - 1ull));
            keptL[ki] = l; keptT[ki] = t; keptR[ki] = rr;
            keptB[ki] = bb; keptA[ki] = area;
        }
        nkept += (unsigned)__popcll(keepw);
        __syncthreads();

        // outputs for my member (class blocks partition the 1000 ranks)
        if (act) {
            float kf = ((keepw >> lane) & 1ull) ? 1.0f : 0.0f;
            size_t o = (size_t)b * K_N + r;
            out_boxes[o * 4 + 0] = bx.x * kf;
            out_boxes[o * 4 + 1] = bx.y * kf;
            out_boxes[o * 4 + 2] = bx.z * kf;
            out_boxes[o * 4 + 3] = bx.w * kf;
            out_scores[o] = sc * kf;
            out_keep[o] = kf;
        }
    }
}

// ---------------------------------------------------------------- launch
extern "C" void kernel_launch(void* const* d_in, const int* in_sizes, int n_in,
                              void* d_out, int out_size, void* d_ws, size_t ws_size,
                              hipStream_t stream)
{
    const float* ptxywh  = (const float*)d_in[0];
    const float* pcls    = (const float*)d_in[1];
    const float* anchors = (const float*)d_in[2];
    float* out = (float*)d_out;

    char* ws = (char*)d_ws;
    size_t o = 0;
    float* pscore = (float*)(ws + o);        o += (size_t)B_N * A_N * 4;        // 4.16 MB
    u64* winuns   = (u64*)(ws + o);          o += (size_t)B_N * CAND_MAX * 8;   // 8.39 MB
    unsigned* ncand = (unsigned*)(ws + o);   o += 256;
    float* topv = (float*)(ws + o);          o += (size_t)B_N * K_N * 4;
    float4* boxesws = (float4*)(ws + o);     o += (size_t)B_N * K_N * 16;
    int* labelsws   = (int*)(ws + o);        o += (size_t)B_N * K_N * 4;

    int total = B_N * A_N;
    k1_score<<<2048, 256, 0, stream>>>(pcls, pscore, total);
    k2_select<<<B_N, 1024, 0, stream>>>(pscore, winuns, ncand);
    k2c_rank_decode<<<dim3(8, B_N), 1024, 0, stream>>>(winuns, ncand, ptxywh, pcls,
                                                       anchors, topv, boxesws,
                                                       labelsws, out);
    k45_nms<<<dim3(20, B_N), 64, 0, stream>>>(topv, boxesws, labelsws, out);
}

// Round 10
// 73.409 us; speedup vs baseline: 2.5587x; 1.0341x over previous
//
#include <hip/hip_runtime.h>
#include <hip/hip_bf16.h>

#pragma clang fp contract(off)

#define B_N 32
#define A_N 32526
#define C_N 20
#define K_N 1000
#define CAND_MAX 32768   // worst case: all scores equal -> all candidates
#define LIVE_MAX 4096    // LDS live-set capacity for the fast descent path

typedef unsigned long long u64;

// ---------------------------------------------------------------- kernel 1
// pscore[b,a] = sigmoid(max_c logits)  (sigmoid monotone => max commutes).
// Coalesced: 1280 contiguous float4 loads per 256-anchor block, staged to
// LDS rows at stride 21 words (21 coprime 32 -> conflict-free row reads).
__global__ void __launch_bounds__(256)
k1_score(const float* __restrict__ pcls, float* __restrict__ pscore, int total)
{
    __shared__ float sbuf[256 * 21];
    const int base = blockIdx.x * 256;
    const int lim = min(256, total - base);
    const int nf4 = lim * 5;

    const float4* src = (const float4*)(pcls + (size_t)base * C_N);
    for (int p = threadIdx.x; p < nf4; p += 256) {
        float4 v = src[p];
        int anc = p / 5, part = p - anc * 5;
        float* d = &sbuf[anc * 21 + part * 4];
        d[0] = v.x; d[1] = v.y; d[2] = v.z; d[3] = v.w;
    }
    __syncthreads();

    const int t = threadIdx.x;
    if (t < lim) {
        const float* row = &sbuf[t * 21];
        float m = -INFINITY;
#pragma unroll
        for (int k = 0; k < 20; ++k) m = fmaxf(m, row[k]);
        double e = exp(-(double)m);     // correctly-rounded f32 sigmoid path
        pscore[base + t] = (float)(1.0 / (1.0 + e));
    }
}

// ---------------------------------------------------------------- kernel 2
// per batch: V = exact 1000th-largest score VALUE via 2-bit descent,
// seeded at the first differing score bit (AND/OR prefix reduce), with
// adaptive live-set compaction (live <= 4096 -> 4 keys/thread in regs).
__global__ void __launch_bounds__(1024)
k2_select(const float* __restrict__ pscore,
          u64* __restrict__ winuns, unsigned* __restrict__ ncand)
{
    const int b = blockIdx.x;
    const int tid = threadIdx.x, lane = tid & 63, wv = tid >> 6;
    __shared__ u64 wsum[2][16];
    __shared__ u64 lkey[LIVE_MAX];
    __shared__ unsigned cnt_s;

    const float* ps = pscore + (size_t)b * A_N;
    unsigned key[32];                        // coalesced: a = tid + i*1024
#pragma unroll
    for (int i = 0; i < 32; ++i) {
        int a = tid + i * 1024;
        key[i] = (a < A_N) ? __float_as_uint(ps[a]) : 0u;
    }

    int slot = 0;
    // block-wide 3-count packed sum; one barrier; broadcast LDS reads
    auto bs3 = [&](unsigned a, unsigned b2, unsigned c) -> u64 {
        u64 s = (u64)a | ((u64)b2 << 21) | ((u64)c << 42);
#pragma unroll
        for (int off = 32; off > 0; off >>= 1) s += __shfl_down(s, off);
        if (lane == 0) wsum[slot][wv] = s;
        __syncthreads();
        u64 t = 0;
#pragma unroll
        for (int w = 0; w < 16; ++w) t += wsum[slot][w];
        slot ^= 1;
        return t;
    };

    // ---- seed: common prefix of all score keys (pads = 0 participate in
    // OR only via 0, in AND we must exclude them -> use key|~valid trick:
    // pad AND-identity = ~0, OR-identity = 0)
    unsigned kand = 0xFFFFFFFFu, kor = 0u;
#pragma unroll
    for (int i = 0; i < 32; ++i) {
        int a = tid + i * 1024;
        unsigned k = key[i];
        kand &= (a < A_N) ? k : 0xFFFFFFFFu;
        kor  |= k;
    }
    {
        u64 pk = ((u64)kand << 32) | (u64)kor;
#pragma unroll
        for (int off = 32; off > 0; off >>= 1) {
            u64 o = __shfl_down(pk, off);
            pk = ((pk & o) & 0xFFFFFFFF00000000ull) | ((pk | o) & 0xFFFFFFFFull);
        }
        if (lane == 0) wsum[slot][wv] = pk;
        __syncthreads();
        u64 t2and = 0xFFFFFFFF00000000ull, t2or = 0ull;
#pragma unroll
        for (int w = 0; w < 16; ++w) {
            u64 o = wsum[slot][w];
            t2and &= (o & 0xFFFFFFFF00000000ull);
            t2or  |= (o & 0xFFFFFFFFull);
        }
        slot ^= 1;
        kand = (unsigned)(t2and >> 32);
        kor  = (unsigned)t2or;
    }

    unsigned V;
    unsigned live = A_N;
    int sh;
    if (kand == kor) {
        V = kand;            // all keys identical
        sh = -1;
    } else {
        unsigned diff = kand ^ kor;
        int h = 31 - __builtin_clz(diff);        // highest differing bit (<=29)
        V = kor & ~((h >= 31) ? 0u : ((1u << (h + 1)) - 1u)); // common prefix
        sh = (h & 1) ? h - 1 : h;
        // single-bit round at odd h first
        if (h & 1) {
            unsigned X = V | (1u << h);
            unsigned c = 0;
#pragma unroll
            for (int i = 0; i < 32; ++i) c += (key[i] >= X);
            u64 s = bs3(c, 0, 0);
            unsigned s1 = (unsigned)(s & 0x1FFFFFu);
            if (s1 >= K_N) { V = X; live = s1; }
        }
    }

    // phase 1: full-register rounds (32 keys/thread) while live set large
#pragma unroll 1
    while (sh >= 0 && live > LIVE_MAX) {
        unsigned X1 = V | (1u << sh), X2 = V | (2u << sh), X3 = V | (3u << sh);
        unsigned c1 = 0, c2 = 0, c3 = 0;
#pragma unroll
        for (int i = 0; i < 32; ++i) {
            unsigned k = key[i];
            c1 += (k >= X1); c2 += (k >= X2); c3 += (k >= X3);
        }
        u64 s = bs3(c1, c2, c3);
        unsigned s1 = (unsigned)(s & 0x1FFFFFu);
        unsigned s2 = (unsigned)((s >> 21) & 0x1FFFFFu);
        unsigned s3 = (unsigned)(s >> 42);
        if (s3 >= K_N)      { V = X3; live = s3; }
        else if (s2 >= K_N) { V = X2; live = s2; }
        else if (s1 >= K_N) { V = X1; live = s1; }
        sh -= 2;
    }

    u64* wb = winuns + (size_t)b * CAND_MAX;

    if (sh >= 0) {
        // ---- fast path: compact live keys (>= V) to LDS, 4 regs/thread ----
        if (tid == 0) cnt_s = 0;
        __syncthreads();
#pragma unroll
        for (int i = 0; i < 32; ++i) {
            int a = tid + i * 1024;
            bool liv = (a < A_N) && (key[i] >= V);
            u64 wm = __ballot(liv);
            unsigned base = 0;
            if (lane == 0 && wm) base = atomicAdd(&cnt_s, (unsigned)__popcll(wm));
            base = __shfl(base, 0);
            if (liv)
                lkey[base + (unsigned)__popcll(wm & ((1ull << lane) - 1ull))] =
                    ((u64)key[i] << 32) | (u64)(0xFFFFFFFFu - (unsigned)a);
        }
        __syncthreads();
        const unsigned nl = cnt_s;          // == live <= LIVE_MAX
        u64 kk0 = (tid          < nl) ? lkey[tid]          : 0ull;
        u64 kk1 = (tid + 1024u  < nl) ? lkey[tid + 1024]   : 0ull;
        u64 kk2 = (tid + 2048u  < nl) ? lkey[tid + 2048]   : 0ull;
        u64 kk3 = (tid + 3072u  < nl) ? lkey[tid + 3072]   : 0ull;

        // phase 2: barrier-floor rounds on <= 4 keys/thread
#pragma unroll 1
        while (sh >= 0) {
            u64 X1 = (u64)(V | (1u << sh)) << 32;
            u64 X2 = (u64)(V | (2u << sh)) << 32;
            u64 X3 = (u64)(V | (3u << sh)) << 32;
            unsigned c1 = (kk0 >= X1) + (kk1 >= X1) + (kk2 >= X1) + (kk3 >= X1);
            unsigned c2 = (kk0 >= X2) + (kk1 >= X2) + (kk2 >= X2) + (kk3 >= X2);
            unsigned c3 = (kk0 >= X3) + (kk1 >= X3) + (kk2 >= X3) + (kk3 >= X3);
            u64 s = bs3(c1, c2, c3);
            unsigned s1 = (unsigned)(s & 0x1FFFFFu);
            unsigned s2 = (unsigned)((s >> 21) & 0x1FFFFFu);
            unsigned s3 = (unsigned)(s >> 42);
            if (s3 >= K_N)      V = (unsigned)(X3 >> 32);
            else if (s2 >= K_N) V = (unsigned)(X2 >> 32);
            else if (s1 >= K_N) V = (unsigned)(X1 >> 32);
            sh -= 2;
        }

        // final compaction of winners (score >= V) from the 4 registers
        if (tid == 0) cnt_s = 0;
        __syncthreads();
        const u64 VV = (u64)V << 32;
        u64 kk[4] = {kk0, kk1, kk2, kk3};
#pragma unroll
        for (int i = 0; i < 4; ++i) {
            bool win = kk[i] >= VV;          // pads are 0 -> never win
            u64 wm = __ballot(win);
            unsigned base = 0;
            if (lane == 0 && wm) base = atomicAdd(&cnt_s, (unsigned)__popcll(wm));
            base = __shfl(base, 0);
            if (win)
                wb[base + (unsigned)__popcll(wm & ((1ull << lane) - 1ull))] = kk[i];
        }
        __syncthreads();
        if (tid == 0) ncand[b] = cnt_s;
    } else {
        // ---- fallback (mass ties; never hit on bench data): register path ----
        if (tid == 0) cnt_s = 0;
        __syncthreads();
#pragma unroll
        for (int i = 0; i < 32; ++i) {
            int a = tid + i * 1024;
            bool win = (a < A_N) && (key[i] >= V);
            u64 wm = __ballot(win);
            unsigned base = 0;
            if (lane == 0 && wm) base = atomicAdd(&cnt_s, (unsigned)__popcll(wm));
            base = __shfl(base, 0);
            if (win)
                wb[base + (unsigned)__popcll(wm & ((1ull << lane) - 1ull))] =
                    ((u64)key[i] << 32) | (u64)(0xFFFFFFFFu - (unsigned)a);
        }
        __syncthreads();
        if (tid == 0) ncand[b] = cnt_s;
    }
}

// ---------------------------------------------------------------- kernel 2c
// rank candidates by full unique key; ranks < 1000 also decode (fused k3).
__global__ void __launch_bounds__(1024)
k2c_rank_decode(const u64* __restrict__ winuns, const unsigned* __restrict__ ncand,
                const float* __restrict__ ptxywh,
                const float* __restrict__ pcls,
                const float* __restrict__ anchors,
                float* __restrict__ topv,
                float4* __restrict__ boxesws,
                int* __restrict__ labelsws,
                float* __restrict__ out)
{
    const int bc = blockIdx.x;   // 0..7
    const int b = blockIdx.y;
    const int tid = threadIdx.x;
    __shared__ u64 chunk[1024];
    const unsigned n = ncand[b];
    const u64* wb = winuns + (size_t)b * CAND_MAX;

    const int wl = tid >> 3;     // winner slot within pass: 0..127
    const int seg = tid & 7;

    for (unsigned w0 = bc * 128u; w0 < n; w0 += 1024u) {
        unsigned w = w0 + (unsigned)wl;
        bool act = (w < n);
        u64 myk = act ? wb[w] : 0ull;
        unsigned cnt = 0;
        for (unsigned j0 = 0; j0 < n; j0 += 1024u) {
            __syncthreads();
            unsigned j = j0 + tid;
            chunk[tid] = (j < n) ? wb[j] : 0ull;   // pad 0: never > myk
            __syncthreads();
            const ulonglong2* c2p = (const ulonglong2*)chunk;
#pragma unroll 16
            for (int jj = 0; jj < 64; ++jj) {
                ulonglong2 p = c2p[jj * 8 + seg];
                cnt += (p.x > myk) + (p.y > myk);
            }
        }
        cnt += __shfl_xor(cnt, 1);
        cnt += __shfl_xor(cnt, 2);
        cnt += __shfl_xor(cnt, 4);
        if (act && seg == 0 && cnt < K_N) {
            unsigned rank = cnt;
            int a = (int)(0xFFFFFFFFu - (unsigned)(myk & 0xFFFFFFFFull));
            size_t t = (size_t)b * K_N + rank;
            topv[t] = __uint_as_float((unsigned)(myk >> 32));

            // ---- fused decode (exact former-k3 math) ----
            float4 tb = ((const float4*)ptxywh)[(size_t)b * A_N + a];
            float4 an = ((const float4*)anchors)[a];
            float xx = an.x + (tb.x * 0.1f) * an.z;
            float yy = an.y + (tb.y * 0.1f) * an.w;
            float ww = an.z * (float)exp((double)(tb.z * 0.2f));
            float hh = an.w * (float)exp((double)(tb.w * 0.2f));
            float hw = ww * 0.5f, hh2 = hh * 0.5f;
            boxesws[t] = make_float4(xx - hw, yy - hh2, xx + hw, yy + hh2);

            const float4* pc = (const float4*)(pcls + ((size_t)b * A_N + a) * C_N);
            float m = -INFINITY; int lab = 0;
#pragma unroll
            for (int q = 0; q < 5; ++q) {
                float4 v = pc[q];
                if (v.x > m) { m = v.x; lab = q * 4 + 0; }
                if (v.y > m) { m = v.y; lab = q * 4 + 1; }
                if (v.z > m) { m = v.z; lab = q * 4 + 2; }
                if (v.w > m) { m = v.w; lab = q * 4 + 3; }
            }
            labelsws[t] = lab + 1;

            out[t] = (float)b;                          // ids_batch
            out[5 * B_N * K_N + t] = (float)(lab + 1);  // labels
        }
    }
}

// ---------------------------------------------------------------- kernel 45
// per-(batch, class) greedy NMS (cross-class IoU exactly 0 after +10*label
// offset; stable class grouping preserves rank order within class -> bit-
// identical to the global 1000-step greedy). One wave per (b, class).
__global__ void __launch_bounds__(64)
k45_nms(const float* __restrict__ topv,
        const float4* __restrict__ boxesws,
        const int* __restrict__ labelsws,
        float* __restrict__ out)
{
    const int c = blockIdx.x + 1;       // class 1..20
    const int b = blockIdx.y;
    const int lane = threadIdx.x;       // 64 threads = 1 wave

    __shared__ unsigned short mem[K_N];
    __shared__ float keptL[K_N], keptT[K_N], keptR[K_N], keptB[K_N], keptA[K_N];

    const int*    labs = labelsws + (size_t)b * K_N;
    const float*  tv   = topv     + (size_t)b * K_N;
    const float4* bw   = boxesws  + (size_t)b * K_N;

    // gather this class's members in rank order (stable ballot compaction)
    unsigned nmem = 0;
#pragma unroll 1
    for (int r0 = 0; r0 < K_N; r0 += 64) {
        int r = r0 + lane;
        bool is = (r < K_N) && (labs[r] == c);
        u64 bm = __ballot(is);
        if (is) mem[nmem + (unsigned)__popcll(bm & ((1ull << lane) - 1ull))] =
                    (unsigned short)r;
        nmem += (unsigned)__popcll(bm);
    }
    __syncthreads();

    const float off = (float)c * 10.0f;
    unsigned nkept = 0;

    float* out_boxes  = out + (size_t)B_N * K_N;          // 32000
    float* out_scores = out + (size_t)6 * B_N * K_N;      // 192000
    float* out_keep   = out + (size_t)7 * B_N * K_N;      // 224000

#pragma unroll 1
    for (unsigned q0 = 0; q0 < nmem; q0 += 64) {
        unsigned midx = q0 + (unsigned)lane;
        bool act = midx < nmem;
        int r = act ? (int)mem[midx] : 0;
        float4 bx = bw[r];
        // offset box + area, exact reference op order
        float l  = bx.x + off, t = bx.y + off;
        float rr = bx.z + off, bb = bx.w + off;
        float area = (rr - l) * (bb - t);
        float sc = tv[r];
        bool valid = act && (sc >= 0.5f);

        // suppression by earlier-chunk kept boxes
        bool supp = false;
#pragma unroll 1
        for (unsigned k = 0; k < nkept; ++k) {
            float lx = fmaxf(keptL[k], l);
            float ly = fmaxf(keptT[k], t);
            float rx = fminf(keptR[k], rr);
            float ry = fminf(keptB[k], bb);
            float wx = fmaxf(rx - lx, 0.0f);
            float wy = fmaxf(ry - ly, 0.0f);
            float inter = wx * wy;
            float uni = keptA[k] + area - inter;
            float iou = inter / fmaxf(uni, 1e-9f);
            supp |= (iou > 0.5f);
        }

        // intra-chunk greedy, class-rank order, on-the-fly IoU
        u64 todo = __ballot(valid && !supp);
        u64 keepw = 0ull;
        while (todo) {
            int i = (int)__builtin_ctzll(todo);
            todo &= todo - 1ull;
            keepw |= (1ull << i);
            float bl = __shfl(l, i),  bt  = __shfl(t, i);
            float br = __shfl(rr, i), bbo = __shfl(bb, i);
            float ba = __shfl(area, i);
            float lx = fmaxf(bl, l),  ly = fmaxf(bt, t);
            float rx = fminf(br, rr), ry = fminf(bbo, bb);
            float wx = fmaxf(rx - lx, 0.0f), wy = fmaxf(ry - ly, 0.0f);
            float inter = wx * wy;
            float uni = ba + area - inter;
            float iou = inter / fmaxf(uni, 1e-9f);
            u64 sm = __ballot((iou > 0.5f) && (lane != i));
            todo &= ~sm;
        }

        // append kept boxes to LDS list
        if ((keepw >> lane) & 1ull) {
            unsigned ki = nkept + (unsigned)__popcll(keepw & ((1ull << lane) - 1ull));
            keptL[ki] = l; keptT[ki] = t; keptR[ki] = rr;
            keptB[ki] = bb; keptA[ki] = area;
        }
        nkept += (unsigned)__popcll(keepw);
        __syncthreads();

        // outputs for my member (class blocks partition the 1000 ranks)
        if (act) {
            float kf = ((keepw >> lane) & 1ull) ? 1.0f : 0.0f;
            size_t o = (size_t)b * K_N + r;
            out_boxes[o * 4 + 0] = bx.x * kf;
            out_boxes[o * 4 + 1] = bx.y * kf;
            out_boxes[o * 4 + 2] = bx.z * kf;
            out_boxes[o * 4 + 3] = bx.w * kf;
            out_scores[o] = sc * kf;
            out_keep[o] = kf;
        }
    }
}

// ---------------------------------------------------------------- launch
extern "C" void kernel_launch(void* const* d_in, const int* in_sizes, int n_in,
                              void* d_out, int out_size, void* d_ws, size_t ws_size,
                              hipStream_t stream)
{
    const float* ptxywh  = (const float*)d_in[0];
    const float* pcls    = (const float*)d_in[1];
    const float* anchors = (const float*)d_in[2];
    float* out = (float*)d_out;

    char* ws = (char*)d_ws;
    size_t o = 0;
    float* pscore = (float*)(ws + o);        o += (size_t)B_N * A_N * 4;        // 4.16 MB
    u64* winuns   = (u64*)(ws + o);          o += (size_t)B_N * CAND_MAX * 8;   // 8.39 MB
    unsigned* ncand = (unsigned*)(ws + o);   o += 256;
    float* topv = (float*)(ws + o);          o += (size_t)B_N * K_N * 4;
    float4* boxesws = (float4*)(ws + o);     o += (size_t)B_N * K_N * 16;
    int* labelsws   = (int*)(ws + o);        o += (size_t)B_N * K_N * 4;

    int total = B_N * A_N;
    k1_score<<<(total + 255) / 256, 256, 0, stream>>>(pcls, pscore, total);
    k2_select<<<B_N, 1024, 0, stream>>>(pscore, winuns, ncand);
    k2c_rank_decode<<<dim3(8, B_N), 1024, 0, stream>>>(winuns, ncand, ptxywh, pcls,
                                                       anchors, topv, boxesws,
                                                       labelsws, out);
    k45_nms<<<dim3(20, B_N), 64, 0, stream>>>(topv, boxesws, labelsws, out);
}